// Round 5
// baseline (49444.363 us; speedup 1.0000x reference)
//
#include <hip/hip_runtime.h>
#include <hip/hip_bf16.h>
#include <stdint.h>

#define T_STEPS 8192
#define HID     1024
#define IN_F    2048
#define N3H     3072   // 3*HID
#define NREP    16     // exchange-buffer replicas

// ---------------------------------------------------------------------------
// Exchange format: one u32 per h element; low 2 mantissa bits = step tag
// (step & 3). Double-buffered (buffer s&1 holds h of step s); stale content
// is from step s-2 (tag differs mod 4). NREP replicas: producer wave stores
// its word to all replicas (one instruction, lanes 0..NREP-1); consumer wave
// gw polls replica gw&(NREP-1) only. Fused tag+data: a wave's step-i data
// reads ARE its detect, and its step-(i+1) store certifies it finished
// reading step i -> 2-buffer protocol race-free at any skew (mod-4 tag).
// h_0 = 0.0f with tag 0 == 0x0 -> zero-init.
// ---------------------------------------------------------------------------
__global__ void init_pairs(unsigned int* pairs) {
    int i = blockIdx.x * blockDim.x + threadIdx.x;
    if (i < 2 * NREP * HID) pairs[i] = 0u;
}

// Batched scoped poll: 4x dwordx4 (the wave's full 4 KB view of h), single
// vmcnt wait. Per-32-bit-word atomicity from natural alignment; tearing
// across words is harmless (each word carries its own tag).
__device__ __forceinline__ void load_h_scoped(const unsigned int* p,
                                              uint4& a, uint4& b, uint4& c, uint4& d) {
    asm volatile(
        "global_load_dwordx4 %0, %4, off sc0 sc1\n\t"
        "global_load_dwordx4 %1, %4, off offset:1024 sc0 sc1\n\t"
        "global_load_dwordx4 %2, %4, off offset:2048 sc0 sc1\n\t"
        "global_load_dwordx4 %3, %4, off offset:3072 sc0 sc1\n\t"
        "s_waitcnt vmcnt(0)"
        : "=v"(a), "=v"(b), "=v"(c), "=v"(d) : "v"(p) : "memory");
}
__device__ __forceinline__ void store_scoped(unsigned int* p, unsigned int v) {
    asm volatile("global_store_dword %0, %1, off sc0 sc1"
                 :: "v"(p), "v"(v) : "memory");
}

// ---------------------------------------------------------------------------
// Phase 1: gi GEMM (unchanged, ~1.4 ms)
// ---------------------------------------------------------------------------
#define GBM 64
#define GBN 64
#define GBK 32

__global__ __launch_bounds__(256) void gi_gemm(
    const float* __restrict__ feat,   // [8192][2048]
    const float* __restrict__ rew,    // [8192]
    const float* __restrict__ w_ih,   // [3072][2049]
    const float* __restrict__ b_ih,   // [3072]
    float* __restrict__ gi)           // [8192][3072]
{
    __shared__ float As[GBK][GBM + 4];
    __shared__ float Bs[GBK][GBN + 4];

    const int tid = threadIdx.x;
    const int n0 = blockIdx.x * GBN;
    const int t0 = blockIdx.y * GBM;
    const int tx = tid & 15, ty = tid >> 4;
    const int lr = tid >> 3;
    const int lc = (tid & 7) * 4;

    float acc[4][4] = {{0.f}};

    for (int k0 = 0; k0 < IN_F; k0 += GBK) {
#pragma unroll
        for (int hh = 0; hh < 2; hh++) {
            const int r = lr + 32 * hh;
            const float4 a = *(const float4*)(feat + (size_t)(t0 + r) * IN_F + k0 + lc);
            As[lc + 0][r] = a.x; As[lc + 1][r] = a.y;
            As[lc + 2][r] = a.z; As[lc + 3][r] = a.w;
            const float* brow = w_ih + (size_t)(n0 + r) * (IN_F + 1) + k0 + lc;
            Bs[lc + 0][r] = brow[0]; Bs[lc + 1][r] = brow[1];
            Bs[lc + 2][r] = brow[2]; Bs[lc + 3][r] = brow[3];
        }
        __syncthreads();
#pragma unroll
        for (int kk = 0; kk < GBK; kk++) {
            const float4 a = *(const float4*)&As[kk][ty * 4];
            const float4 b = *(const float4*)&Bs[kk][tx * 4];
            acc[0][0] += a.x * b.x; acc[0][1] += a.x * b.y; acc[0][2] += a.x * b.z; acc[0][3] += a.x * b.w;
            acc[1][0] += a.y * b.x; acc[1][1] += a.y * b.y; acc[1][2] += a.y * b.z; acc[1][3] += a.y * b.w;
            acc[2][0] += a.z * b.x; acc[2][1] += a.z * b.y; acc[2][2] += a.z * b.z; acc[2][3] += a.z * b.w;
            acc[3][0] += a.w * b.x; acc[3][1] += a.w * b.y; acc[3][2] += a.w * b.z; acc[3][3] += a.w * b.w;
        }
        __syncthreads();
    }

    const int m = t0 + ty * 4;
    const int n = n0 + tx * 4;
    float wlast[4], bi[4];
#pragma unroll
    for (int c = 0; c < 4; c++) {
        wlast[c] = w_ih[(size_t)(n + c) * (IN_F + 1) + IN_F];
        bi[c]    = b_ih[n + c];
    }
#pragma unroll
    for (int r = 0; r < 4; r++) {
        const float rwv = rew[m + r];
        float4 v;
        v.x = acc[r][0] + rwv * wlast[0] + bi[0];
        v.y = acc[r][1] + rwv * wlast[1] + bi[1];
        v.z = acc[r][2] + rwv * wlast[2] + bi[2];
        v.w = acc[r][3] + rwv * wlast[3] + bi[3];
        *(float4*)(gi + (size_t)(m + r) * N3H + n) = v;
    }
}

// ---------------------------------------------------------------------------
// DPP wave-64 sum -> lane 63 (VALU pipe only); verified correct in round 3.
// ---------------------------------------------------------------------------
__device__ __forceinline__ float wave_red_sum(float x) {
    int v;
    v = __builtin_amdgcn_update_dpp(0, __float_as_int(x), 0x111, 0xf, 0xf, true); // row_shr:1
    x += __int_as_float(v);
    v = __builtin_amdgcn_update_dpp(0, __float_as_int(x), 0x112, 0xf, 0xf, true); // row_shr:2
    x += __int_as_float(v);
    v = __builtin_amdgcn_update_dpp(0, __float_as_int(x), 0x114, 0xf, 0xf, true); // row_shr:4
    x += __int_as_float(v);
    v = __builtin_amdgcn_update_dpp(0, __float_as_int(x), 0x118, 0xf, 0xf, true); // row_shr:8
    x += __int_as_float(v);
    v = __builtin_amdgcn_update_dpp(0, __float_as_int(x), 0x142, 0xf, 0xf, true); // row_bcast:15
    x += __int_as_float(v);
    v = __builtin_amdgcn_update_dpp(0, __float_as_int(x), 0x143, 0xf, 0xf, true); // row_bcast:31
    x += __int_as_float(v);
    return x;
}
__device__ __forceinline__ float bcast_lane(float x, int lane) {
    return __int_as_float(__builtin_amdgcn_readlane(__float_as_int(x), lane));
}

// ---------------------------------------------------------------------------
// Phase 2: wave-autonomous GRU scan. 256 wgs x 256 thr = 1024 waves; wave gw
// owns output j=gw. Its 3 recurrent weight rows live in 12 float4 registers
// (48 VGPRs -- no demotion risk). Zero LDS, zero barriers: poll straight
// into registers, FMA, DPP-reduce, broadcast, one replica-fanout store.
// ---------------------------------------------------------------------------
__global__ __launch_bounds__(256, 1) void gru_scan(
    const float* __restrict__ gi,     // [8192][3072]
    const float* __restrict__ w_hh,   // [3072][1024]
    const float* __restrict__ b_hh,   // [3072]
    unsigned int* pairs,              // [2][NREP][1024] tagged fp32
    float* __restrict__ out)          // [1024]
{
    const int tid  = threadIdx.x;
    const int lane = tid & 63;
    const int j    = blockIdx.x * 4 + (tid >> 6);   // global wave id == output idx
    const int rep  = j & (NREP - 1);

#define LW(g, m4) (*(const float4*)(w_hh + (size_t)((g) * HID + j) * HID + 4 * (lane + 64 * (m4))))
    const float4 wr0 = LW(0, 0), wr1 = LW(0, 1), wr2 = LW(0, 2), wr3 = LW(0, 3);
    const float4 wz0 = LW(1, 0), wz1 = LW(1, 1), wz2 = LW(1, 2), wz3 = LW(1, 3);
    const float4 wn0 = LW(2, 0), wn1 = LW(2, 1), wn2 = LW(2, 2), wn3 = LW(2, 3);
#undef LW
    const float b_r = b_hh[j];
    const float b_z = b_hh[HID + j];
    const float b_n = b_hh[2 * HID + j];

    // locate h_old[j] inside the polled fragments (all wave-uniform):
    const int m4s  = j >> 8;          // which fragment register
    const int cmps = j & 3;           // which float4 component
    const int lsrc = (j >> 2) & 63;   // which lane

    unsigned int* const outbase = pairs;  // [2][NREP][1024]

    for (int i = 0; i < T_STEPS; i++) {
        const int t = T_STEPS - 1 - i;
        const unsigned int* rbuf =
            outbase + ((size_t)(i & 1) * NREP + rep) * HID;

        // gi prefetch (wave-uniform broadcast loads; overlap the poll wait)
        const float* girow = gi + (size_t)t * N3H;
        const float gi_r = girow[j];
        const float gi_z = girow[HID + j];
        const float gi_n = girow[2 * HID + j];

        // poll full h into registers until all 16 words carry tag (i&3)
        const unsigned int want = (unsigned int)(i & 3);
        uint4 v0, v1, v2, v3;
        for (;;) {
            load_h_scoped(rbuf + 4 * lane, v0, v1, v2, v3);
            unsigned int m = 0;
            m |= (v0.x & 3u) ^ want; m |= (v0.y & 3u) ^ want;
            m |= (v0.z & 3u) ^ want; m |= (v0.w & 3u) ^ want;
            m |= (v1.x & 3u) ^ want; m |= (v1.y & 3u) ^ want;
            m |= (v1.z & 3u) ^ want; m |= (v1.w & 3u) ^ want;
            m |= (v2.x & 3u) ^ want; m |= (v2.y & 3u) ^ want;
            m |= (v2.z & 3u) ^ want; m |= (v2.w & 3u) ^ want;
            m |= (v3.x & 3u) ^ want; m |= (v3.y & 3u) ^ want;
            m |= (v3.z & 3u) ^ want; m |= (v3.w & 3u) ^ want;
            if (m == 0) break;
            __builtin_amdgcn_s_sleep(1);
        }
        const float4 h0 = make_float4(__uint_as_float(v0.x), __uint_as_float(v0.y),
                                      __uint_as_float(v0.z), __uint_as_float(v0.w));
        const float4 h1 = make_float4(__uint_as_float(v1.x), __uint_as_float(v1.y),
                                      __uint_as_float(v1.z), __uint_as_float(v1.w));
        const float4 h2 = make_float4(__uint_as_float(v2.x), __uint_as_float(v2.y),
                                      __uint_as_float(v2.z), __uint_as_float(v2.w));
        const float4 h3 = make_float4(__uint_as_float(v3.x), __uint_as_float(v3.y),
                                      __uint_as_float(v3.z), __uint_as_float(v3.w));

        // 3 gate dot-partials (48 FMA/lane) from registers
        float ar, az, an;
        ar  = h0.x * wr0.x + h0.y * wr0.y + h0.z * wr0.z + h0.w * wr0.w;
        az  = h0.x * wz0.x + h0.y * wz0.y + h0.z * wz0.z + h0.w * wz0.w;
        an  = h0.x * wn0.x + h0.y * wn0.y + h0.z * wn0.z + h0.w * wn0.w;
        ar += h1.x * wr1.x + h1.y * wr1.y + h1.z * wr1.z + h1.w * wr1.w;
        az += h1.x * wz1.x + h1.y * wz1.y + h1.z * wz1.z + h1.w * wz1.w;
        an += h1.x * wn1.x + h1.y * wn1.y + h1.z * wn1.z + h1.w * wn1.w;
        ar += h2.x * wr2.x + h2.y * wr2.y + h2.z * wr2.z + h2.w * wr2.w;
        az += h2.x * wz2.x + h2.y * wz2.y + h2.z * wz2.z + h2.w * wz2.w;
        an += h2.x * wn2.x + h2.y * wn2.y + h2.z * wn2.z + h2.w * wn2.w;
        ar += h3.x * wr3.x + h3.y * wr3.y + h3.z * wr3.z + h3.w * wr3.w;
        az += h3.x * wz3.x + h3.y * wz3.y + h3.z * wz3.z + h3.w * wz3.w;
        an += h3.x * wn3.x + h3.y * wn3.y + h3.z * wn3.z + h3.w * wn3.w;

        const float sr = bcast_lane(wave_red_sum(ar), 63);
        const float sz = bcast_lane(wave_red_sum(az), 63);
        const float sn = bcast_lane(wave_red_sum(an), 63);

        // previous h for my j (wave-uniform selects + readlane)
        const float4 hsrc = (m4s == 0) ? h0 : (m4s == 1) ? h1 : (m4s == 2) ? h2 : h3;
        const float hcomp = (cmps == 0) ? hsrc.x : (cmps == 1) ? hsrc.y
                          : (cmps == 2) ? hsrc.z : hsrc.w;
        const float hold = bcast_lane(hcomp, lsrc);

        // gates (all lanes redundantly; no divergence)
        const float r = 1.f / (1.f + __expf(-(gi_r + sr + b_r)));
        const float z = 1.f / (1.f + __expf(-(gi_z + sz + b_z)));
        const float n = tanhf(gi_n + r * (sn + b_n));
        const float hnew = (1.f - z) * n + z * hold;

        if (i == T_STEPS - 1) {
            if (lane == 0) out[j] = hnew;
        } else if (lane < NREP) {
            const unsigned int pk =
                (__float_as_uint(hnew) & ~3u) | (unsigned int)((i + 1) & 3);
            unsigned int* nbuf = outbase + (size_t)((i + 1) & 1) * NREP * HID;
            store_scoped(nbuf + lane * HID + j, pk);   // lanes 0..15 -> 16 replicas
        }
    }
}

// ---------------------------------------------------------------------------
extern "C" void kernel_launch(void* const* d_in, const int* in_sizes, int n_in,
                              void* d_out, int out_size, void* d_ws, size_t ws_size,
                              hipStream_t stream) {
    const float* feat = (const float*)d_in[0];  // [8192,2048]
    const float* rew  = (const float*)d_in[1];  // [8192]
    const float* w_ih = (const float*)d_in[2];  // [3072,2049]
    const float* w_hh = (const float*)d_in[3];  // [3072,1024]
    const float* b_ih = (const float*)d_in[4];  // [3072]
    const float* b_hh = (const float*)d_in[5];  // [3072]
    float* out = (float*)d_out;                 // [1024]

    float* gi = (float*)d_ws;                                   // 96 MB
    unsigned int* pairs =
        (unsigned int*)((char*)d_ws + (size_t)T_STEPS * N3H * sizeof(float));  // 128 KB

    hipLaunchKernelGGL(init_pairs, dim3((2 * NREP * HID + 255) / 256), dim3(256), 0, stream, pairs);
    hipLaunchKernelGGL(gi_gemm, dim3(N3H / GBN, T_STEPS / GBM), dim3(256), 0, stream,
                       feat, rew, w_ih, b_ih, gi);
    hipLaunchKernelGGL(gru_scan, dim3(256), dim3(256), 0, stream,
                       gi, w_hh, b_hh, pairs, out);
}

// Round 6
// 48311.938 us; speedup vs baseline: 1.0234x; 1.0234x over previous
//
#include <hip/hip_runtime.h>
#include <hip/hip_bf16.h>
#include <stdint.h>

#define T_STEPS 8192
#define HID     1024
#define IN_F    2048
#define N3H     3072   // 3*HID
#define NREP    16     // exchange-buffer replicas

// ---------------------------------------------------------------------------
// Exchange format: one u32 per h element; low 2 mantissa bits = step tag
// (step & 3). Double-buffered (buffer s&1 holds h of step s); stale content
// is from step s-2 (tag differs mod 4). NREP replicas: producer wave stores
// its word to all replicas in ONE instruction (lanes 0..NREP-1); consumer
// wave j polls replica j&(NREP-1) only. Fused tag+data keeps the 2-buffer
// protocol race-free at any skew. h_0 = 0.0f with tag 0 == 0x0 -> zero-init.
// ---------------------------------------------------------------------------
__global__ void init_pairs(unsigned int* pairs) {
    int i = blockIdx.x * blockDim.x + threadIdx.x;
    if (i < 2 * NREP * HID) pairs[i] = 0u;
}

// Batched scoped poll: 4x dwordx4 (wave covers the full 4 KB replica),
// single vmcnt wait. Per-dword atomicity from natural alignment; tearing
// across words is harmless (each word carries its own tag).
__device__ __forceinline__ void load_h_scoped(const unsigned int* p,
                                              uint4& a, uint4& b, uint4& c, uint4& d) {
    asm volatile(
        "global_load_dwordx4 %0, %4, off sc0 sc1\n\t"
        "global_load_dwordx4 %1, %4, off offset:1024 sc0 sc1\n\t"
        "global_load_dwordx4 %2, %4, off offset:2048 sc0 sc1\n\t"
        "global_load_dwordx4 %3, %4, off offset:3072 sc0 sc1\n\t"
        "s_waitcnt vmcnt(0)"
        : "=v"(a), "=v"(b), "=v"(c), "=v"(d) : "v"(p) : "memory");
}
__device__ __forceinline__ void store_scoped(unsigned int* p, unsigned int v) {
    asm volatile("global_store_dword %0, %1, off sc0 sc1"
                 :: "v"(p), "v"(v) : "memory");
}

// ---------------------------------------------------------------------------
// Phase 1: gi GEMM (unchanged; ~1.4 ms, ~74 TF fp32)
// ---------------------------------------------------------------------------
#define GBM 64
#define GBN 64
#define GBK 32

__global__ __launch_bounds__(256) void gi_gemm(
    const float* __restrict__ feat,   // [8192][2048]
    const float* __restrict__ rew,    // [8192]
    const float* __restrict__ w_ih,   // [3072][2049]
    const float* __restrict__ b_ih,   // [3072]
    float* __restrict__ gi)           // [8192][3072]
{
    __shared__ float As[GBK][GBM + 4];
    __shared__ float Bs[GBK][GBN + 4];

    const int tid = threadIdx.x;
    const int n0 = blockIdx.x * GBN;
    const int t0 = blockIdx.y * GBM;
    const int tx = tid & 15, ty = tid >> 4;
    const int lr = tid >> 3;
    const int lc = (tid & 7) * 4;

    float acc[4][4] = {{0.f}};

    for (int k0 = 0; k0 < IN_F; k0 += GBK) {
#pragma unroll
        for (int hh = 0; hh < 2; hh++) {
            const int r = lr + 32 * hh;
            const float4 a = *(const float4*)(feat + (size_t)(t0 + r) * IN_F + k0 + lc);
            As[lc + 0][r] = a.x; As[lc + 1][r] = a.y;
            As[lc + 2][r] = a.z; As[lc + 3][r] = a.w;
            const float* brow = w_ih + (size_t)(n0 + r) * (IN_F + 1) + k0 + lc;
            Bs[lc + 0][r] = brow[0]; Bs[lc + 1][r] = brow[1];
            Bs[lc + 2][r] = brow[2]; Bs[lc + 3][r] = brow[3];
        }
        __syncthreads();
#pragma unroll
        for (int kk = 0; kk < GBK; kk++) {
            const float4 a = *(const float4*)&As[kk][ty * 4];
            const float4 b = *(const float4*)&Bs[kk][tx * 4];
            acc[0][0] += a.x * b.x; acc[0][1] += a.x * b.y; acc[0][2] += a.x * b.z; acc[0][3] += a.x * b.w;
            acc[1][0] += a.y * b.x; acc[1][1] += a.y * b.y; acc[1][2] += a.y * b.z; acc[1][3] += a.y * b.w;
            acc[2][0] += a.z * b.x; acc[2][1] += a.z * b.y; acc[2][2] += a.z * b.z; acc[2][3] += a.z * b.w;
            acc[3][0] += a.w * b.x; acc[3][1] += a.w * b.y; acc[3][2] += a.w * b.z; acc[3][3] += a.w * b.w;
        }
        __syncthreads();
    }

    const int m = t0 + ty * 4;
    const int n = n0 + tx * 4;
    float wlast[4], bi[4];
#pragma unroll
    for (int c = 0; c < 4; c++) {
        wlast[c] = w_ih[(size_t)(n + c) * (IN_F + 1) + IN_F];
        bi[c]    = b_ih[n + c];
    }
#pragma unroll
    for (int r = 0; r < 4; r++) {
        const float rwv = rew[m + r];
        float4 v;
        v.x = acc[r][0] + rwv * wlast[0] + bi[0];
        v.y = acc[r][1] + rwv * wlast[1] + bi[1];
        v.z = acc[r][2] + rwv * wlast[2] + bi[2];
        v.w = acc[r][3] + rwv * wlast[3] + bi[3];
        *(float4*)(gi + (size_t)(m + r) * N3H + n) = v;
    }
}

// ---------------------------------------------------------------------------
// DPP wave-64 sum -> full sum in lane 63 (VALU pipe; verified round 3/5).
// ---------------------------------------------------------------------------
__device__ __forceinline__ float wave_red_sum(float x) {
    int v;
    v = __builtin_amdgcn_update_dpp(0, __float_as_int(x), 0x111, 0xf, 0xf, true); // row_shr:1
    x += __int_as_float(v);
    v = __builtin_amdgcn_update_dpp(0, __float_as_int(x), 0x112, 0xf, 0xf, true); // row_shr:2
    x += __int_as_float(v);
    v = __builtin_amdgcn_update_dpp(0, __float_as_int(x), 0x114, 0xf, 0xf, true); // row_shr:4
    x += __int_as_float(v);
    v = __builtin_amdgcn_update_dpp(0, __float_as_int(x), 0x118, 0xf, 0xf, true); // row_shr:8
    x += __int_as_float(v);
    v = __builtin_amdgcn_update_dpp(0, __float_as_int(x), 0x142, 0xf, 0xf, true); // row_bcast:15
    x += __int_as_float(v);
    v = __builtin_amdgcn_update_dpp(0, __float_as_int(x), 0x143, 0xf, 0xf, true); // row_bcast:31
    x += __int_as_float(v);
    return x;
}
__device__ __forceinline__ float bcast_lane(float x, int lane) {
    return __int_as_float(__builtin_amdgcn_readlane(__float_as_int(x), lane));
}

// ---------------------------------------------------------------------------
// Phase 2: barrier-free wave-autonomous GRU scan, weights in LDS.
// 256 wgs x 256 thr = 1024 waves; wave (g,w) owns j = 4g+w. Its 3 recurrent
// weight rows live in LDS (12 KB/wave, 48 KB/wg, read-only after init -> no
// loop barriers, no VGPR-demotion risk). Poll full tagged h straight into
// registers, dot vs LDS weights, DPP-reduce, single replica-fanout store.
// ---------------------------------------------------------------------------
__global__ __launch_bounds__(256, 1) void gru_scan(
    const float* __restrict__ gi,     // [8192][3072]
    const float* __restrict__ w_hh,   // [3072][1024]
    const float* __restrict__ b_hh,   // [3072]
    unsigned int* pairs,              // [2][NREP][1024] tagged fp32
    float* __restrict__ out)          // [1024]
{
    __shared__ float4 w_lds[4][3][HID / 4];  // [j_local][gate][k/4]  48 KB

    const int tid  = threadIdx.x;
    const int lane = tid & 63;
    const int wave = tid >> 6;
    const int g    = blockIdx.x;
    const int j    = g * 4 + wave;                 // this wave's output index
    const int rep  = j & (NREP - 1);

    // stage 12 weight rows (4 j_local x 3 gates) into LDS, coalesced
#pragma unroll
    for (int idx = 0; idx < 12; idx++) {
        const int jl = idx >> 2, gt = idx & 3;     // note: gt in 0..3? no ->
    }
    // (explicit staging: idx = jl*3+gt)
#pragma unroll
    for (int idx = 0; idx < 12; idx++) {
        const int jl = idx / 3, gt = idx % 3;
        const float4* src = (const float4*)(w_hh + (size_t)(gt * HID + g * 4 + jl) * HID);
        w_lds[jl][gt][tid] = src[tid];
    }
    const float b_r = b_hh[j];
    const float b_z = b_hh[HID + j];
    const float b_n = b_hh[2 * HID + j];
    __syncthreads();   // weights ready; the ONLY barrier

    // locate h_old[j] inside the polled fragments (wave-uniform):
    const int m4s  = j >> 8;          // which fragment
    const int cmps = j & 3;           // which float4 component
    const int lsrc = (j >> 2) & 63;   // which lane

    const float4* const wr = w_lds[wave][0];
    const float4* const wz = w_lds[wave][1];
    const float4* const wn = w_lds[wave][2];

    for (int i = 0; i < T_STEPS; i++) {
        const int t = T_STEPS - 1 - i;
        const unsigned int* rbuf = pairs + ((size_t)(i & 1) * NREP + rep) * HID;

        // gi prefetch (independent; overlaps the poll wait)
        const float* girow = gi + (size_t)t * N3H;
        const float gi_r = girow[j];
        const float gi_z = girow[HID + j];
        const float gi_n = girow[2 * HID + j];

        // poll full h into registers until all 16 words carry tag (i&3)
        const unsigned int want = (unsigned int)(i & 3);
        uint4 v0, v1, v2, v3;
        for (;;) {
            load_h_scoped(rbuf + 4 * lane, v0, v1, v2, v3);
            unsigned int m;
            m  = (v0.x ^ want) | (v0.y ^ want) | (v0.z ^ want) | (v0.w ^ want);
            m |= (v1.x ^ want) | (v1.y ^ want) | (v1.z ^ want) | (v1.w ^ want);
            m |= (v2.x ^ want) | (v2.y ^ want) | (v2.z ^ want) | (v2.w ^ want);
            m |= (v3.x ^ want) | (v3.y ^ want) | (v3.z ^ want) | (v3.w ^ want);
            if ((m & 3u) == 0u) break;
            __builtin_amdgcn_s_sleep(1);
        }
        const float4 h0 = make_float4(__uint_as_float(v0.x), __uint_as_float(v0.y),
                                      __uint_as_float(v0.z), __uint_as_float(v0.w));
        const float4 h1 = make_float4(__uint_as_float(v1.x), __uint_as_float(v1.y),
                                      __uint_as_float(v1.z), __uint_as_float(v1.w));
        const float4 h2 = make_float4(__uint_as_float(v2.x), __uint_as_float(v2.y),
                                      __uint_as_float(v2.z), __uint_as_float(v2.w));
        const float4 h3 = make_float4(__uint_as_float(v3.x), __uint_as_float(v3.y),
                                      __uint_as_float(v3.z), __uint_as_float(v3.w));

        // 3 gate dot-partials: 12 ds_read_b128 + 48 FMA/lane
        float ar, az, an;
        {
            const float4 a0 = wr[lane], b0 = wz[lane], c0 = wn[lane];
            ar  = h0.x * a0.x + h0.y * a0.y + h0.z * a0.z + h0.w * a0.w;
            az  = h0.x * b0.x + h0.y * b0.y + h0.z * b0.z + h0.w * b0.w;
            an  = h0.x * c0.x + h0.y * c0.y + h0.z * c0.z + h0.w * c0.w;
            const float4 a1 = wr[lane + 64], b1 = wz[lane + 64], c1 = wn[lane + 64];
            ar += h1.x * a1.x + h1.y * a1.y + h1.z * a1.z + h1.w * a1.w;
            az += h1.x * b1.x + h1.y * b1.y + h1.z * b1.z + h1.w * b1.w;
            an += h1.x * c1.x + h1.y * c1.y + h1.z * c1.z + h1.w * c1.w;
            const float4 a2 = wr[lane + 128], b2 = wz[lane + 128], c2 = wn[lane + 128];
            ar += h2.x * a2.x + h2.y * a2.y + h2.z * a2.z + h2.w * a2.w;
            az += h2.x * b2.x + h2.y * b2.y + h2.z * b2.z + h2.w * b2.w;
            an += h2.x * c2.x + h2.y * c2.y + h2.z * c2.z + h2.w * c2.w;
            const float4 a3 = wr[lane + 192], b3 = wz[lane + 192], c3 = wn[lane + 192];
            ar += h3.x * a3.x + h3.y * a3.y + h3.z * a3.z + h3.w * a3.w;
            az += h3.x * b3.x + h3.y * b3.y + h3.z * b3.z + h3.w * b3.w;
            an += h3.x * c3.x + h3.y * c3.y + h3.z * c3.z + h3.w * c3.w;
        }

        const float sr = bcast_lane(wave_red_sum(ar), 63);
        const float sz = bcast_lane(wave_red_sum(az), 63);
        const float sn = bcast_lane(wave_red_sum(an), 63);

        // previous h for my j (wave-uniform selects + readlane)
        const float4 hsrc = (m4s == 0) ? h0 : (m4s == 1) ? h1 : (m4s == 2) ? h2 : h3;
        const float hcomp = (cmps == 0) ? hsrc.x : (cmps == 1) ? hsrc.y
                          : (cmps == 2) ? hsrc.z : hsrc.w;
        const float hold = bcast_lane(hcomp, lsrc);

        // gates (all lanes redundantly; no divergence)
        const float r = 1.f / (1.f + __expf(-(gi_r + sr + b_r)));
        const float z = 1.f / (1.f + __expf(-(gi_z + sz + b_z)));
        const float n = tanhf(gi_n + r * (sn + b_n));
        const float hnew = (1.f - z) * n + z * hold;

        if (i == T_STEPS - 1) {
            if (lane == 0) out[j] = hnew;
        } else if (lane < NREP) {
            const unsigned int pk =
                (__float_as_uint(hnew) & ~3u) | (unsigned int)((i + 1) & 3);
            unsigned int* nbuf = pairs + (size_t)((i + 1) & 1) * NREP * HID;
            store_scoped(nbuf + lane * HID + j, pk);   // lanes 0..15 -> 16 replicas
        }
    }
}

// ---------------------------------------------------------------------------
extern "C" void kernel_launch(void* const* d_in, const int* in_sizes, int n_in,
                              void* d_out, int out_size, void* d_ws, size_t ws_size,
                              hipStream_t stream) {
    const float* feat = (const float*)d_in[0];  // [8192,2048]
    const float* rew  = (const float*)d_in[1];  // [8192]
    const float* w_ih = (const float*)d_in[2];  // [3072,2049]
    const float* w_hh = (const float*)d_in[3];  // [3072,1024]
    const float* b_ih = (const float*)d_in[4];  // [3072]
    const float* b_hh = (const float*)d_in[5];  // [3072]
    float* out = (float*)d_out;                 // [1024]

    float* gi = (float*)d_ws;                                   // 96 MB
    unsigned int* pairs =
        (unsigned int*)((char*)d_ws + (size_t)T_STEPS * N3H * sizeof(float));  // 128 KB

    hipLaunchKernelGGL(init_pairs, dim3((2 * NREP * HID + 255) / 256), dim3(256), 0, stream, pairs);
    hipLaunchKernelGGL(gi_gemm, dim3(N3H / GBN, T_STEPS / GBM), dim3(256), 0, stream,
                       feat, rew, w_ih, b_ih, gi);
    hipLaunchKernelGGL(gru_scan, dim3(256), dim3(256), 0, stream,
                       gi, w_hh, b_hh, pairs, out);
}

// Round 7
// 25744.739 us; speedup vs baseline: 1.9206x; 1.8766x over previous
//
#include <hip/hip_runtime.h>
#include <hip/hip_bf16.h>
#include <stdint.h>

#define T_STEPS 8192
#define HID     1024
#define IN_F    2048
#define N3H     3072   // 3*HID
#define NREP    16     // exchange-buffer replicas

// ---------------------------------------------------------------------------
// Exchange format: one u32 per h element; low 2 mantissa bits = step tag
// (step & 3). Double-buffered (buffer s&1 holds h of step s); stale content
// is from step s-2 (tag differs mod 4). NREP replicas: producer wave stores
// its word to all replicas in ONE instruction (lanes 0..15); consumer wg g
// polls replica g&15 only. Fused tag+data keeps the 2-buffer protocol
// race-free at any skew. h_0 = 0.0f with tag 0 == 0x0 -> zero-init.
// ---------------------------------------------------------------------------
__global__ void init_pairs(unsigned int* pairs) {
    int i = blockIdx.x * blockDim.x + threadIdx.x;
    if (i < 2 * NREP * HID) pairs[i] = 0u;
}

// Scoped 16 B load (bypass L1/L2 so cross-XCD stores are visible). Per-dword
// atomicity from natural alignment; tearing across words is harmless (each
// word carries its own tag).
__device__ __forceinline__ uint4 load_x4_scoped(const unsigned int* p) {
    uint4 r;
    asm volatile("global_load_dwordx4 %0, %1, off sc0 sc1\n\t"
                 "s_waitcnt vmcnt(0)"
                 : "=v"(r) : "v"(p) : "memory");
    return r;
}
__device__ __forceinline__ void store_scoped(unsigned int* p, unsigned int v) {
    asm volatile("global_store_dword %0, %1, off sc0 sc1"
                 :: "v"(p), "v"(v) : "memory");
}

// ---------------------------------------------------------------------------
// Phase 1: gi GEMM (unchanged; ~1.4 ms, ~74 TF fp32)
// ---------------------------------------------------------------------------
#define GBM 64
#define GBN 64
#define GBK 32

__global__ __launch_bounds__(256) void gi_gemm(
    const float* __restrict__ feat,   // [8192][2048]
    const float* __restrict__ rew,    // [8192]
    const float* __restrict__ w_ih,   // [3072][2049]
    const float* __restrict__ b_ih,   // [3072]
    float* __restrict__ gi)           // [8192][3072]
{
    __shared__ float As[GBK][GBM + 4];
    __shared__ float Bs[GBK][GBN + 4];

    const int tid = threadIdx.x;
    const int n0 = blockIdx.x * GBN;
    const int t0 = blockIdx.y * GBM;
    const int tx = tid & 15, ty = tid >> 4;
    const int lr = tid >> 3;
    const int lc = (tid & 7) * 4;

    float acc[4][4] = {{0.f}};

    for (int k0 = 0; k0 < IN_F; k0 += GBK) {
#pragma unroll
        for (int hh = 0; hh < 2; hh++) {
            const int r = lr + 32 * hh;
            const float4 a = *(const float4*)(feat + (size_t)(t0 + r) * IN_F + k0 + lc);
            As[lc + 0][r] = a.x; As[lc + 1][r] = a.y;
            As[lc + 2][r] = a.z; As[lc + 3][r] = a.w;
            const float* brow = w_ih + (size_t)(n0 + r) * (IN_F + 1) + k0 + lc;
            Bs[lc + 0][r] = brow[0]; Bs[lc + 1][r] = brow[1];
            Bs[lc + 2][r] = brow[2]; Bs[lc + 3][r] = brow[3];
        }
        __syncthreads();
#pragma unroll
        for (int kk = 0; kk < GBK; kk++) {
            const float4 a = *(const float4*)&As[kk][ty * 4];
            const float4 b = *(const float4*)&Bs[kk][tx * 4];
            acc[0][0] += a.x * b.x; acc[0][1] += a.x * b.y; acc[0][2] += a.x * b.z; acc[0][3] += a.x * b.w;
            acc[1][0] += a.y * b.x; acc[1][1] += a.y * b.y; acc[1][2] += a.y * b.z; acc[1][3] += a.y * b.w;
            acc[2][0] += a.z * b.x; acc[2][1] += a.z * b.y; acc[2][2] += a.z * b.z; acc[2][3] += a.z * b.w;
            acc[3][0] += a.w * b.x; acc[3][1] += a.w * b.y; acc[3][2] += a.w * b.z; acc[3][3] += a.w * b.w;
        }
        __syncthreads();
    }

    const int m = t0 + ty * 4;
    const int n = n0 + tx * 4;
    float wlast[4], bi[4];
#pragma unroll
    for (int c = 0; c < 4; c++) {
        wlast[c] = w_ih[(size_t)(n + c) * (IN_F + 1) + IN_F];
        bi[c]    = b_ih[n + c];
    }
#pragma unroll
    for (int r = 0; r < 4; r++) {
        const float rwv = rew[m + r];
        float4 v;
        v.x = acc[r][0] + rwv * wlast[0] + bi[0];
        v.y = acc[r][1] + rwv * wlast[1] + bi[1];
        v.z = acc[r][2] + rwv * wlast[2] + bi[2];
        v.w = acc[r][3] + rwv * wlast[3] + bi[3];
        *(float4*)(gi + (size_t)(m + r) * N3H + n) = v;
    }
}

// ---------------------------------------------------------------------------
// DPP wave-64 sum -> full sum in lane 63 (VALU pipe; verified rounds 3/5/6).
// ---------------------------------------------------------------------------
__device__ __forceinline__ float wave_red_sum(float x) {
    int v;
    v = __builtin_amdgcn_update_dpp(0, __float_as_int(x), 0x111, 0xf, 0xf, true); // row_shr:1
    x += __int_as_float(v);
    v = __builtin_amdgcn_update_dpp(0, __float_as_int(x), 0x112, 0xf, 0xf, true); // row_shr:2
    x += __int_as_float(v);
    v = __builtin_amdgcn_update_dpp(0, __float_as_int(x), 0x114, 0xf, 0xf, true); // row_shr:4
    x += __int_as_float(v);
    v = __builtin_amdgcn_update_dpp(0, __float_as_int(x), 0x118, 0xf, 0xf, true); // row_shr:8
    x += __int_as_float(v);
    v = __builtin_amdgcn_update_dpp(0, __float_as_int(x), 0x142, 0xf, 0xf, true); // row_bcast:15
    x += __int_as_float(v);
    v = __builtin_amdgcn_update_dpp(0, __float_as_int(x), 0x143, 0xf, 0xf, true); // row_bcast:31
    x += __int_as_float(v);
    return x;
}
__device__ __forceinline__ float bcast_lane(float x, int lane) {
    return __int_as_float(__builtin_amdgcn_readlane(__float_as_int(x), lane));
}

// ---------------------------------------------------------------------------
// Phase 2: persistent GRU scan (r4 skeleton + serial-chain cuts).
// 256 wgs x 256 thr; wave w of wg g owns j = 4g+w. Weights in static LDS
// (48 KB). Cooperative poll: each thread 1 dwordx4 -> wg covers h once per
// attempt (minimal coherence-point footprint -- the proven r4 shape).
// Double-buffered h staging -> ONE barrier per step. DPP reduce (VALU pipe).
// All-lane gate compute -> single-instruction 16-replica fanout store.
// ---------------------------------------------------------------------------
__global__ __launch_bounds__(256, 2) void gru_scan(
    const float* __restrict__ gi,     // [8192][3072]
    const float* __restrict__ w_hh,   // [3072][1024]
    const float* __restrict__ b_hh,   // [3072]
    unsigned int* pairs,              // [2][NREP][1024] tagged fp32
    float* __restrict__ out)          // [1024]
{
    __shared__ float4 w_lds[3][4][HID / 4];  // [gate][j_local][k/4]  48 KB
    __shared__ float4 h_lds[2][HID / 4];     // double-buffered h      8 KB

    const int tid  = threadIdx.x;
    const int g    = blockIdx.x;      // 0..255
    const int j0   = g * 4;
    const int wave = tid >> 6;
    const int lane = tid & 63;
    const int myj  = j0 + wave;
    const int rep  = g & (NREP - 1);

    // stage this wg's 12 weight rows into LDS (r4-proven layout)
#pragma unroll
    for (int r = 0; r < 12; r++) {
        const int gate = r >> 2, jl = r & 3;
        const float4* src = (const float4*)(w_hh + (size_t)(gate * HID + j0 + jl) * HID);
        w_lds[gate][jl][tid] = src[tid];
    }
    // biases: wave-uniform loads into all lanes
    const float b_r = b_hh[myj];
    const float b_z = b_hh[HID + myj];
    const float b_n = b_hh[2 * HID + myj];
    __syncthreads();

    const float4* const wr = w_lds[0][wave];
    const float4* const wz = w_lds[1][wave];
    const float4* const wn = w_lds[2][wave];

    for (int i = 0; i < T_STEPS; i++) {
        const int t = T_STEPS - 1 - i;
        const unsigned int* rbuf = pairs + ((size_t)(i & 1) * NREP + rep) * HID;

        // gi prefetch (wave-uniform; issued before the spin)
        const float* girow = gi + (size_t)t * N3H;
        const float gi_r = girow[myj];
        const float gi_z = girow[HID + myj];
        const float gi_n = girow[2 * HID + myj];

        // cooperative poll: one dwordx4 per thread until all 4 words tagged
        {
            const unsigned int want = (unsigned int)(i & 3);
            uint4 v;
            for (;;) {
                v = load_x4_scoped(rbuf + tid * 4);
                const unsigned int m = (v.x ^ want) | (v.y ^ want) |
                                       (v.z ^ want) | (v.w ^ want);
                if ((m & 3u) == 0u) break;
                __builtin_amdgcn_s_sleep(1);
            }
            float4 hv;
            hv.x = __uint_as_float(v.x);
            hv.y = __uint_as_float(v.y);
            hv.z = __uint_as_float(v.z);
            hv.w = __uint_as_float(v.w);
            h_lds[i & 1][tid] = hv;
        }
        __syncthreads();   // the ONLY barrier per step (h_lds double-buffered)

        // wave computes 3 recurrent dots for j = myj from LDS
        const float4* hb = h_lds[i & 1];
        float ar = 0.f, az = 0.f, an = 0.f;
#pragma unroll
        for (int m4 = 0; m4 < 4; m4++) {
            const int idx = lane + 64 * m4;
            const float4 h4 = hb[idx];
            const float4 r4 = wr[idx];
            const float4 z4 = wz[idx];
            const float4 n4 = wn[idx];
            ar += h4.x * r4.x + h4.y * r4.y + h4.z * r4.z + h4.w * r4.w;
            az += h4.x * z4.x + h4.y * z4.y + h4.z * z4.z + h4.w * z4.w;
            an += h4.x * n4.x + h4.y * n4.y + h4.z * n4.z + h4.w * n4.w;
        }

        // DPP reduce (VALU) -> lane63 -> broadcast to all lanes
        const float sr = bcast_lane(wave_red_sum(ar), 63);
        const float sz = bcast_lane(wave_red_sum(az), 63);
        const float sn = bcast_lane(wave_red_sum(an), 63);

        // previous h for my j: LDS broadcast read (same addr, all lanes)
        const float hold = ((const float*)hb)[myj];

        // gates computed redundantly in all lanes (wave-uniform, no divergence)
        const float r = 1.f / (1.f + __expf(-(gi_r + sr + b_r)));
        const float z = 1.f / (1.f + __expf(-(gi_z + sz + b_z)));
        const float n = tanhf(gi_n + r * (sn + b_n));
        const float hnew = (1.f - z) * n + z * hold;

        if (i == T_STEPS - 1) {
            if (lane == 0) out[myj] = hnew;
        } else if (lane < NREP) {
            // pack tag, fan out to all 16 replicas in ONE instruction
            const unsigned int pk =
                (__float_as_uint(hnew) & ~3u) | (unsigned int)((i + 1) & 3);
            unsigned int* nbuf = pairs + (size_t)((i + 1) & 1) * NREP * HID;
            store_scoped(nbuf + lane * HID + myj, pk);
        }
    }
}

// ---------------------------------------------------------------------------
extern "C" void kernel_launch(void* const* d_in, const int* in_sizes, int n_in,
                              void* d_out, int out_size, void* d_ws, size_t ws_size,
                              hipStream_t stream) {
    const float* feat = (const float*)d_in[0];  // [8192,2048]
    const float* rew  = (const float*)d_in[1];  // [8192]
    const float* w_ih = (const float*)d_in[2];  // [3072,2049]
    const float* w_hh = (const float*)d_in[3];  // [3072,1024]
    const float* b_ih = (const float*)d_in[4];  // [3072]
    const float* b_hh = (const float*)d_in[5];  // [3072]
    float* out = (float*)d_out;                 // [1024]

    float* gi = (float*)d_ws;                                   // 96 MB
    unsigned int* pairs =
        (unsigned int*)((char*)d_ws + (size_t)T_STEPS * N3H * sizeof(float));  // 128 KB

    hipLaunchKernelGGL(init_pairs, dim3((2 * NREP * HID + 255) / 256), dim3(256), 0, stream, pairs);
    hipLaunchKernelGGL(gi_gemm, dim3(N3H / GBN, T_STEPS / GBM), dim3(256), 0, stream,
                       feat, rew, w_ih, b_ih, gi);
    hipLaunchKernelGGL(gru_scan, dim3(256), dim3(256), 0, stream,
                       gi, w_hh, b_hh, pairs, out);
}

// Round 8
// 22548.326 us; speedup vs baseline: 2.1928x; 1.1418x over previous
//
#include <hip/hip_runtime.h>
#include <hip/hip_bf16.h>
#include <stdint.h>

#define T_STEPS 8192
#define HID     1024
#define IN_F    2048
#define N3H     3072   // 3*HID
#define NREP    8      // exchange-buffer replicas
#define NWG     128    // scan workgroups (wg owns 8 j's; wave owns 2)

// ---------------------------------------------------------------------------
// Exchange format: one u32 per h element; low 2 mantissa bits = step tag
// (step & 3). Double-buffered (buffer s&1 holds h of step s); stale content
// is from step s-2 (tag differs mod 4). NREP replicas: producer wave stores
// its TWO adjacent words to all replicas in ONE instruction (lanes 0..15:
// replica=lane>>1, word=lane&1); consumer wg g polls replica g&7 only.
// Fused tag+data keeps the 2-buffer protocol race-free at any skew.
// h_0 = 0.0f with tag 0 == 0x0 -> zero-init.
// ---------------------------------------------------------------------------
__global__ void init_pairs(unsigned int* pairs) {
    int i = blockIdx.x * blockDim.x + threadIdx.x;
    if (i < 2 * NREP * HID) pairs[i] = 0u;
}

// Scoped 16 B load (L1/L2-bypassing so cross-XCD stores are visible).
// Per-dword atomicity from natural alignment; cross-word tearing harmless
// (each word carries its own tag).
__device__ __forceinline__ uint4 load_x4_scoped(const unsigned int* p) {
    uint4 r;
    asm volatile("global_load_dwordx4 %0, %1, off sc0 sc1\n\t"
                 "s_waitcnt vmcnt(0)"
                 : "=v"(r) : "v"(p) : "memory");
    return r;
}
__device__ __forceinline__ void store_scoped(unsigned int* p, unsigned int v) {
    asm volatile("global_store_dword %0, %1, off sc0 sc1"
                 :: "v"(p), "v"(v) : "memory");
}

// ---------------------------------------------------------------------------
// Phase 1: gi GEMM (unchanged; ~1.4 ms, ~74 TF fp32)
// ---------------------------------------------------------------------------
#define GBM 64
#define GBN 64
#define GBK 32

__global__ __launch_bounds__(256) void gi_gemm(
    const float* __restrict__ feat,   // [8192][2048]
    const float* __restrict__ rew,    // [8192]
    const float* __restrict__ w_ih,   // [3072][2049]
    const float* __restrict__ b_ih,   // [3072]
    float* __restrict__ gi)           // [8192][3072]
{
    __shared__ float As[GBK][GBM + 4];
    __shared__ float Bs[GBK][GBN + 4];

    const int tid = threadIdx.x;
    const int n0 = blockIdx.x * GBN;
    const int t0 = blockIdx.y * GBM;
    const int tx = tid & 15, ty = tid >> 4;
    const int lr = tid >> 3;
    const int lc = (tid & 7) * 4;

    float acc[4][4] = {{0.f}};

    for (int k0 = 0; k0 < IN_F; k0 += GBK) {
#pragma unroll
        for (int hh = 0; hh < 2; hh++) {
            const int r = lr + 32 * hh;
            const float4 a = *(const float4*)(feat + (size_t)(t0 + r) * IN_F + k0 + lc);
            As[lc + 0][r] = a.x; As[lc + 1][r] = a.y;
            As[lc + 2][r] = a.z; As[lc + 3][r] = a.w;
            const float* brow = w_ih + (size_t)(n0 + r) * (IN_F + 1) + k0 + lc;
            Bs[lc + 0][r] = brow[0]; Bs[lc + 1][r] = brow[1];
            Bs[lc + 2][r] = brow[2]; Bs[lc + 3][r] = brow[3];
        }
        __syncthreads();
#pragma unroll
        for (int kk = 0; kk < GBK; kk++) {
            const float4 a = *(const float4*)&As[kk][ty * 4];
            const float4 b = *(const float4*)&Bs[kk][tx * 4];
            acc[0][0] += a.x * b.x; acc[0][1] += a.x * b.y; acc[0][2] += a.x * b.z; acc[0][3] += a.x * b.w;
            acc[1][0] += a.y * b.x; acc[1][1] += a.y * b.y; acc[1][2] += a.y * b.z; acc[1][3] += a.y * b.w;
            acc[2][0] += a.z * b.x; acc[2][1] += a.z * b.y; acc[2][2] += a.z * b.z; acc[2][3] += a.z * b.w;
            acc[3][0] += a.w * b.x; acc[3][1] += a.w * b.y; acc[3][2] += a.w * b.z; acc[3][3] += a.w * b.w;
        }
        __syncthreads();
    }

    const int m = t0 + ty * 4;
    const int n = n0 + tx * 4;
    float wlast[4], bi[4];
#pragma unroll
    for (int c = 0; c < 4; c++) {
        wlast[c] = w_ih[(size_t)(n + c) * (IN_F + 1) + IN_F];
        bi[c]    = b_ih[n + c];
    }
#pragma unroll
    for (int r = 0; r < 4; r++) {
        const float rwv = rew[m + r];
        float4 v;
        v.x = acc[r][0] + rwv * wlast[0] + bi[0];
        v.y = acc[r][1] + rwv * wlast[1] + bi[1];
        v.z = acc[r][2] + rwv * wlast[2] + bi[2];
        v.w = acc[r][3] + rwv * wlast[3] + bi[3];
        *(float4*)(gi + (size_t)(m + r) * N3H + n) = v;
    }
}

// ---------------------------------------------------------------------------
// DPP wave-64 sum -> full sum in lane 63 (VALU pipe; verified rounds 3/5-7).
// ---------------------------------------------------------------------------
__device__ __forceinline__ float wave_red_sum(float x) {
    int v;
    v = __builtin_amdgcn_update_dpp(0, __float_as_int(x), 0x111, 0xf, 0xf, true); // row_shr:1
    x += __int_as_float(v);
    v = __builtin_amdgcn_update_dpp(0, __float_as_int(x), 0x112, 0xf, 0xf, true); // row_shr:2
    x += __int_as_float(v);
    v = __builtin_amdgcn_update_dpp(0, __float_as_int(x), 0x114, 0xf, 0xf, true); // row_shr:4
    x += __int_as_float(v);
    v = __builtin_amdgcn_update_dpp(0, __float_as_int(x), 0x118, 0xf, 0xf, true); // row_shr:8
    x += __int_as_float(v);
    v = __builtin_amdgcn_update_dpp(0, __float_as_int(x), 0x142, 0xf, 0xf, true); // row_bcast:15
    x += __int_as_float(v);
    v = __builtin_amdgcn_update_dpp(0, __float_as_int(x), 0x143, 0xf, 0xf, true); // row_bcast:31
    x += __int_as_float(v);
    return x;
}
__device__ __forceinline__ float bcast_lane(float x, int lane) {
    return __int_as_float(__builtin_amdgcn_readlane(__float_as_int(x), lane));
}

// ---------------------------------------------------------------------------
// Phase 2: persistent GRU scan, shrunk machine. NWG=128 wgs x 256 thr;
// wg g owns j in [8g, 8g+8); wave w owns j = 8g+2w, 8g+2w+1. Weights in
// static LDS (96 KB). Cooperative poll (1 dwordx4/thread, wg covers h once).
// One barrier/step (dbuf h staging: intra-wg skew <= 1 step by barrier
// matching, so buffer i&1 is not rewritten before all waves leave step i).
// DPP reduce; all-lane gates; single-instruction 8-replica x 2-word fanout.
// ---------------------------------------------------------------------------
__global__ __launch_bounds__(256, 1) void gru_scan(
    const float* __restrict__ gi,     // [8192][3072]
    const float* __restrict__ w_hh,   // [3072][1024]
    const float* __restrict__ b_hh,   // [3072]
    unsigned int* pairs,              // [2][NREP][1024] tagged fp32
    float* __restrict__ out)          // [1024]
{
    __shared__ float4 w_lds[8][3][HID / 4];  // [j_local][gate][k/4]  96 KB
    __shared__ float4 h_lds[2][HID / 4];     // double-buffered h      8 KB

    const int tid  = threadIdx.x;
    const int g    = blockIdx.x;      // 0..127
    const int j0   = g * 8;
    const int wave = tid >> 6;
    const int lane = tid & 63;
    const int jA   = j0 + wave * 2;   // this wave's two outputs: jA, jA+1
    const int rep  = g & (NREP - 1);

    // stage this wg's 24 weight rows into LDS, coalesced
#pragma unroll
    for (int idx = 0; idx < 24; idx++) {
        const int jl = idx / 3, gt = idx % 3;
        const float4* src = (const float4*)(w_hh + (size_t)(gt * HID + j0 + jl) * HID);
        w_lds[jl][gt][tid] = src[tid];
    }
    // biases for both owned j's (wave-uniform loads, all lanes)
    float bh[2][3];
#pragma unroll
    for (int jj = 0; jj < 2; jj++)
#pragma unroll
        for (int gt = 0; gt < 3; gt++)
            bh[jj][gt] = b_hh[gt * HID + jA + jj];
    __syncthreads();

    const float4* const w00 = w_lds[2 * wave][0];
    const float4* const w01 = w_lds[2 * wave][1];
    const float4* const w02 = w_lds[2 * wave][2];
    const float4* const w10 = w_lds[2 * wave + 1][0];
    const float4* const w11 = w_lds[2 * wave + 1][1];
    const float4* const w12 = w_lds[2 * wave + 1][2];

    for (int i = 0; i < T_STEPS; i++) {
        const int t = T_STEPS - 1 - i;
        const unsigned int* rbuf = pairs + ((size_t)(i & 1) * NREP + rep) * HID;

        // gi prefetch for both j's (wave-uniform; issued before the spin)
        const float* girow = gi + (size_t)t * N3H;
        float gg[2][3];
#pragma unroll
        for (int jj = 0; jj < 2; jj++)
#pragma unroll
            for (int gt = 0; gt < 3; gt++)
                gg[jj][gt] = girow[gt * HID + jA + jj];

        // cooperative poll: one dwordx4 per thread until all 4 words tagged
        {
            const unsigned int want = (unsigned int)(i & 3);
            uint4 v;
            for (;;) {
                v = load_x4_scoped(rbuf + tid * 4);
                const unsigned int m = (v.x ^ want) | (v.y ^ want) |
                                       (v.z ^ want) | (v.w ^ want);
                if ((m & 3u) == 0u) break;
                __builtin_amdgcn_s_sleep(1);
            }
            float4 hv;
            hv.x = __uint_as_float(v.x);
            hv.y = __uint_as_float(v.y);
            hv.z = __uint_as_float(v.z);
            hv.w = __uint_as_float(v.w);
            h_lds[i & 1][tid] = hv;
        }
        __syncthreads();   // the only barrier per step

        // 6 recurrent dots (2 j's x 3 gates) from LDS
        const float4* hb = h_lds[i & 1];
        float a00 = 0.f, a01 = 0.f, a02 = 0.f, a10 = 0.f, a11 = 0.f, a12 = 0.f;
#pragma unroll
        for (int m4 = 0; m4 < 4; m4++) {
            const int idx = lane + 64 * m4;
            const float4 h4 = hb[idx];
            const float4 p0 = w00[idx], p1 = w01[idx], p2 = w02[idx];
            a00 += h4.x * p0.x + h4.y * p0.y + h4.z * p0.z + h4.w * p0.w;
            a01 += h4.x * p1.x + h4.y * p1.y + h4.z * p1.z + h4.w * p1.w;
            a02 += h4.x * p2.x + h4.y * p2.y + h4.z * p2.z + h4.w * p2.w;
            const float4 q0 = w10[idx], q1 = w11[idx], q2 = w12[idx];
            a10 += h4.x * q0.x + h4.y * q0.y + h4.z * q0.z + h4.w * q0.w;
            a11 += h4.x * q1.x + h4.y * q1.y + h4.z * q1.z + h4.w * q1.w;
            a12 += h4.x * q2.x + h4.y * q2.y + h4.z * q2.z + h4.w * q2.w;
        }

        // DPP reduce (VALU) -> lane63 -> broadcast
        const float s00 = bcast_lane(wave_red_sum(a00), 63);
        const float s01 = bcast_lane(wave_red_sum(a01), 63);
        const float s02 = bcast_lane(wave_red_sum(a02), 63);
        const float s10 = bcast_lane(wave_red_sum(a10), 63);
        const float s11 = bcast_lane(wave_red_sum(a11), 63);
        const float s12 = bcast_lane(wave_red_sum(a12), 63);

        // previous h (LDS broadcast reads)
        const float holdA = ((const float*)hb)[jA];
        const float holdB = ((const float*)hb)[jA + 1];

        // gates, all lanes (wave-uniform)
        const float rA = 1.f / (1.f + __expf(-(gg[0][0] + s00 + bh[0][0])));
        const float zA = 1.f / (1.f + __expf(-(gg[0][1] + s01 + bh[0][1])));
        const float nA = tanhf(gg[0][2] + rA * (s02 + bh[0][2]));
        const float hnewA = (1.f - zA) * nA + zA * holdA;
        const float rB = 1.f / (1.f + __expf(-(gg[1][0] + s10 + bh[1][0])));
        const float zB = 1.f / (1.f + __expf(-(gg[1][1] + s11 + bh[1][1])));
        const float nB = tanhf(gg[1][2] + rB * (s12 + bh[1][2]));
        const float hnewB = (1.f - zB) * nB + zB * holdB;

        if (i == T_STEPS - 1) {
            if (lane == 0) { out[jA] = hnewA; out[jA + 1] = hnewB; }
        } else if (lane < 2 * NREP) {
            // lanes 0..15: replica = lane>>1, word = lane&1 -> ONE instruction
            const unsigned int tg = (unsigned int)((i + 1) & 3);
            const unsigned int pkA = (__float_as_uint(hnewA) & ~3u) | tg;
            const unsigned int pkB = (__float_as_uint(hnewB) & ~3u) | tg;
            const unsigned int pk = (lane & 1) ? pkB : pkA;
            unsigned int* nbuf = pairs + (size_t)((i + 1) & 1) * NREP * HID;
            store_scoped(nbuf + (lane >> 1) * HID + jA + (lane & 1), pk);
        }
    }
}

// ---------------------------------------------------------------------------
extern "C" void kernel_launch(void* const* d_in, const int* in_sizes, int n_in,
                              void* d_out, int out_size, void* d_ws, size_t ws_size,
                              hipStream_t stream) {
    const float* feat = (const float*)d_in[0];  // [8192,2048]
    const float* rew  = (const float*)d_in[1];  // [8192]
    const float* w_ih = (const float*)d_in[2];  // [3072,2049]
    const float* w_hh = (const float*)d_in[3];  // [3072,1024]
    const float* b_ih = (const float*)d_in[4];  // [3072]
    const float* b_hh = (const float*)d_in[5];  // [3072]
    float* out = (float*)d_out;                 // [1024]

    float* gi = (float*)d_ws;                                   // 96 MB
    unsigned int* pairs =
        (unsigned int*)((char*)d_ws + (size_t)T_STEPS * N3H * sizeof(float));  // 64 KB

    hipLaunchKernelGGL(init_pairs, dim3((2 * NREP * HID + 255) / 256), dim3(256), 0, stream, pairs);
    hipLaunchKernelGGL(gi_gemm, dim3(N3H / GBN, T_STEPS / GBM), dim3(256), 0, stream,
                       feat, rew, w_ih, b_ih, gi);
    hipLaunchKernelGGL(gru_scan, dim3(NWG), dim3(256), 0, stream,
                       gi, w_hh, b_hh, pairs, out);
}